// Round 6
// baseline (66.592 us; speedup 1.0000x reference)
//
#include <hip/hip_runtime.h>

// NegSamplingWord2Vec, latency-optimized v3b:
//   losses[b] = sum_w mask(o_idx!=PAD) * ( softplus(-dot(c,o_w)) +
//                                          sum_k softplus(dot(c,neg_wk)) )
//
// One 256-thread block (4 waves) per batch element. 110 score rows
// (10 words x (1 pos + 10 neg)) padded to 112 = 16 groups x 7 passes.
// Each 16-lane group owns one row per pass; lane gl holds contiguous
// float4 fragments row[gl*4] and row[64+gl*4].
//
// v3: rounds 3-4 showed the compiler sinking the "prefetch" loads back
// to their uses at IR level (VGPR stayed 36-40; sched_barrier only
// fences the machine scheduler). Fix: every fragment component is
// consumed by an empty `asm volatile` AFTER the load loop — a load must
// precede the volatile asm reading its result, so all 14
// global_load_dwordx4 are in flight together and the register file must
// hold the fragments (expect VGPR ~100).
// v3b: scalar asm operands (float4 aggregate is an invalid "v" input).

#define D_DIM   128
#define W_CTX   10
#define K_NEG   10
#define NROWS   110
#define NROWS_P 112
#define NPASS   7
#define BLK     256

__device__ __forceinline__ float fast_softplus(float x) {
    // log(1+exp(x)) via hw v_exp_f32 / v_log_f32
    return fmaxf(x, 0.0f) + __logf(1.0f + __expf(-fabsf(x)));
}

__global__ __launch_bounds__(BLK) void w2v_neg_sampling_kernel(
    const float* __restrict__ center_vectors,
    const float* __restrict__ outside_vectors,
    const int*   __restrict__ center_word_index,
    const int*   __restrict__ outside_word_indices,
    const int*   __restrict__ negative_samples,
    float*       __restrict__ out)
{
    const int b    = blockIdx.x;
    const int tid  = threadIdx.x;
    const int wave = tid >> 6;
    const int lane = tid & 63;
    const int grp  = lane >> 4;   // 0..3 row-group within wave
    const int gl   = lane & 15;   // lane within 16-lane row group

    __shared__ int   s_idx[NROWS_P];
    __shared__ float s_part[4];

    // ---- stage row indices into LDS (slot w*11 = positive/oidx) ----
    if (tid < W_CTX) {
        s_idx[tid * 11] = outside_word_indices[b * W_CTX + tid];
    } else if (tid >= 16 && tid < 16 + W_CTX * K_NEG) {
        const int r = tid - 16;                   // 0..99, coalesced
        const int w = r / K_NEG;
        const int j = r - w * K_NEG;
        s_idx[w * 11 + 1 + j] = negative_samples[b * W_CTX * K_NEG + r];
    } else if (tid >= 128 && tid < 128 + (NROWS_P - NROWS)) {
        s_idx[NROWS + (tid - 128)] = 0;           // pad rows -> row 0
    }
    __syncthreads();

    // ---- center fragment: contiguous float4 pair ----
    const int ci = center_word_index[b];
    const float4* cp = reinterpret_cast<const float4*>(
        center_vectors + (size_t)ci * D_DIM);
    const float4 c0 = cp[gl];
    const float4 c1 = cp[16 + gl];

    // ---- gather my 7 row ids + coefficients ----
    int   idxs[NPASS];
    float cfs[NPASS];
#pragma unroll
    for (int p = 0; p < NPASS; ++p) {
        const int r = p * 16 + wave * 4 + grp;    // unique row in [0,112)
        const int w = r / 11;
        const int j = r - w * 11;
        idxs[p] = s_idx[r];
        const int oi = s_idx[w * 11];             // positive slot = oidx (0 for pads)
        cfs[p] = (oi != 0) ? ((j == 0) ? -1.0f : 1.0f) : 0.0f;
    }

    // ---- issue ALL 14 row-fragment loads ----
    float4 a0[NPASS], a1[NPASS];
#pragma unroll
    for (int p = 0; p < NPASS; ++p) {
        const float4* rp = reinterpret_cast<const float4*>(
            outside_vectors + (size_t)idxs[p] * D_DIM);
        a0[p] = rp[gl];
        a1[p] = rp[16 + gl];
    }
    // Keep-live fence: every component feeds a volatile asm AFTER the load
    // loop, so no load can sink into the compute loop; all 14 stay in
    // flight / live in VGPRs.
#pragma unroll
    for (int p = 0; p < NPASS; ++p) {
        asm volatile("" :: "v"(a0[p].x), "v"(a0[p].y), "v"(a0[p].z), "v"(a0[p].w),
                           "v"(a1[p].x), "v"(a1[p].y), "v"(a1[p].z), "v"(a1[p].w));
    }
    __builtin_amdgcn_sched_barrier(0);

    // ---- compute: dot + 16-lane reduce + softplus per pass ----
    float acc = 0.0f;
#pragma unroll
    for (int p = 0; p < NPASS; ++p) {
        float s = c0.x * a0[p].x;
        s = fmaf(c0.y, a0[p].y, s);
        s = fmaf(c0.z, a0[p].z, s);
        s = fmaf(c0.w, a0[p].w, s);
        s = fmaf(c1.x, a1[p].x, s);
        s = fmaf(c1.y, a1[p].y, s);
        s = fmaf(c1.z, a1[p].z, s);
        s = fmaf(c1.w, a1[p].w, s);

        s += __shfl_xor(s, 8, 64);
        s += __shfl_xor(s, 4, 64);
        s += __shfl_xor(s, 2, 64);
        s += __shfl_xor(s, 1, 64);

        acc += fabsf(cfs[p]) * fast_softplus(cfs[p] * s);
    }

    // acc uniform within each 16-lane group; sum the 4 groups, then 4 waves
    acc += __shfl_xor(acc, 16, 64);
    acc += __shfl_xor(acc, 32, 64);

    if (lane == 0) s_part[wave] = acc;
    __syncthreads();

    if (tid == 0)
        out[b] = s_part[0] + s_part[1] + s_part[2] + s_part[3];
}

extern "C" void kernel_launch(void* const* d_in, const int* in_sizes, int n_in,
                              void* d_out, int out_size, void* d_ws, size_t ws_size,
                              hipStream_t stream) {
    const float* center_vectors       = (const float*)d_in[0];
    const float* outside_vectors      = (const float*)d_in[1];
    const int*   center_word_index    = (const int*)d_in[2];
    const int*   outside_word_indices = (const int*)d_in[3];
    const int*   negative_samples     = (const int*)d_in[4];
    float*       out                  = (float*)d_out;

    const int batch = in_sizes[2];   // 8192

    w2v_neg_sampling_kernel<<<batch, BLK, 0, stream>>>(
        center_vectors, outside_vectors, center_word_index,
        outside_word_indices, negative_samples, out);
}

// Round 7
// 48.921 us; speedup vs baseline: 1.3612x; 1.3612x over previous
//
#include <hip/hip_runtime.h>

// NegSamplingWord2Vec, traffic-optimized (bf16 gather table):
//   losses[b] = sum_w mask(o_idx!=PAD) * ( softplus(-dot(c,o_w)) +
//                                          sum_k softplus(dot(c,neg_wk)) )
//
// Round-6 analysis: kernel runs at FETCH_SIZE/dur = 3.4 TB/s of beyond-L2
// (L3-served) traffic; 213 MB/dispatch of L2 misses is structural — 8 XCDs
// each touch ~68K unique random rows x 512 B with only 4 MB private L2.
// Lever: halve the gathered bytes. Kernel 1 converts outside_vectors to a
// bf16 table in d_ws (RNE); kernel 2 gathers 256 B rows (16 lanes x 16 B).
// Dot error ~sqrt(128)*2^-9 ~ 0.05 absolute vs threshold 17.2.

#define D_DIM   128
#define W_CTX   10
#define K_NEG   10
#define NROWS   110
#define NROWS_P 112
#define NPASS   7
#define BLK     256

__device__ __forceinline__ float fast_softplus(float x) {
    // log(1+exp(x)) via hw v_exp_f32 / v_log_f32
    return fmaxf(x, 0.0f) + __logf(1.0f + __expf(-fabsf(x)));
}

__device__ __forceinline__ unsigned short bf16_rne(float f) {
    unsigned int x = __float_as_uint(f);
    x += 0x7fffu + ((x >> 16) & 1u);
    return (unsigned short)(x >> 16);
}
__device__ __forceinline__ float bflo(unsigned int u) {
    return __uint_as_float(u << 16);
}
__device__ __forceinline__ float bfhi(unsigned int u) {
    return __uint_as_float(u & 0xffff0000u);
}

// ---- kernel 1: f32 table -> bf16 table (RNE), fully streaming ----
__global__ __launch_bounds__(256) void convert_bf16_kernel(
    const float4* __restrict__ src, ushort4* __restrict__ dst, int n4)
{
    const int i = blockIdx.x * 256 + threadIdx.x;
    if (i < n4) {
        const float4 v = src[i];
        ushort4 o;
        o.x = bf16_rne(v.x);
        o.y = bf16_rne(v.y);
        o.z = bf16_rne(v.z);
        o.w = bf16_rne(v.w);
        dst[i] = o;
    }
}

// ---- kernel 2: gather bf16 rows + dot + softplus ----
__global__ __launch_bounds__(BLK) void w2v_bf16_kernel(
    const float*          __restrict__ center_vectors,
    const unsigned short* __restrict__ outside_bf16,
    const int*            __restrict__ center_word_index,
    const int*            __restrict__ outside_word_indices,
    const int*            __restrict__ negative_samples,
    float*                __restrict__ out)
{
    const int b    = blockIdx.x;
    const int tid  = threadIdx.x;
    const int wave = tid >> 6;
    const int lane = tid & 63;
    const int grp  = lane >> 4;   // 0..3 row-group within wave
    const int gl   = lane & 15;   // lane within 16-lane row group

    __shared__ int   s_idx[NROWS_P];
    __shared__ float s_part[4];

    // stage row indices into LDS (slot w*11 = positive/oidx)
    if (tid < W_CTX) {
        s_idx[tid * 11] = outside_word_indices[b * W_CTX + tid];
    } else if (tid >= 16 && tid < 16 + W_CTX * K_NEG) {
        const int r = tid - 16;                   // 0..99, coalesced
        const int w = r / K_NEG;
        const int j = r - w * K_NEG;
        s_idx[w * 11 + 1 + j] = negative_samples[b * W_CTX * K_NEG + r];
    } else if (tid >= 128 && tid < 128 + (NROWS_P - NROWS)) {
        s_idx[NROWS + (tid - 128)] = 0;           // pad rows -> row 0
    }
    __syncthreads();

    // center fragment: elements [gl*8, gl*8+8) as two contiguous float4
    const int ci = center_word_index[b];
    const float4* cp = reinterpret_cast<const float4*>(
        center_vectors + (size_t)ci * D_DIM);
    const float4 c0 = cp[gl * 2];
    const float4 c1 = cp[gl * 2 + 1];

    // my 7 row ids + coefficients
    int   idxs[NPASS];
    float cfs[NPASS];
#pragma unroll
    for (int p = 0; p < NPASS; ++p) {
        const int r = p * 16 + wave * 4 + grp;    // unique row in [0,112)
        const int w = r / 11;
        const int j = r - w * 11;
        idxs[p] = s_idx[r];
        const int oi = s_idx[w * 11];             // positive slot = oidx
        cfs[p] = (oi != 0) ? ((j == 0) ? -1.0f : 1.0f) : 0.0f;
    }

    // issue all 7 row loads (16 B each: 8 bf16 = elems [gl*8, gl*8+8))
    uint4 rv[NPASS];
#pragma unroll
    for (int p = 0; p < NPASS; ++p) {
        rv[p] = reinterpret_cast<const uint4*>(
            outside_bf16 + (size_t)idxs[p] * D_DIM)[gl];
    }
    // loads cannot sink past a may-write-memory asm; all 7 stay in flight
    asm volatile("" ::: "memory");
    __builtin_amdgcn_sched_barrier(0);

    float acc = 0.0f;
#pragma unroll
    for (int p = 0; p < NPASS; ++p) {
        float s = c0.x * bflo(rv[p].x);
        s = fmaf(c0.y, bfhi(rv[p].x), s);
        s = fmaf(c0.z, bflo(rv[p].y), s);
        s = fmaf(c0.w, bfhi(rv[p].y), s);
        s = fmaf(c1.x, bflo(rv[p].z), s);
        s = fmaf(c1.y, bfhi(rv[p].z), s);
        s = fmaf(c1.z, bflo(rv[p].w), s);
        s = fmaf(c1.w, bfhi(rv[p].w), s);

        s += __shfl_xor(s, 8, 64);
        s += __shfl_xor(s, 4, 64);
        s += __shfl_xor(s, 2, 64);
        s += __shfl_xor(s, 1, 64);

        acc += fabsf(cfs[p]) * fast_softplus(cfs[p] * s);
    }

    acc += __shfl_xor(acc, 16, 64);
    acc += __shfl_xor(acc, 32, 64);

    if (lane == 0) s_part[wave] = acc;
    __syncthreads();

    if (tid == 0)
        out[b] = s_part[0] + s_part[1] + s_part[2] + s_part[3];
}

// ---- fallback (round-3 proven f32 kernel) if ws too small ----
__global__ __launch_bounds__(BLK) void w2v_f32_kernel(
    const float* __restrict__ center_vectors,
    const float* __restrict__ outside_vectors,
    const int*   __restrict__ center_word_index,
    const int*   __restrict__ outside_word_indices,
    const int*   __restrict__ negative_samples,
    float*       __restrict__ out)
{
    const int b    = blockIdx.x;
    const int tid  = threadIdx.x;
    const int wave = tid >> 6;
    const int lane = tid & 63;
    const int grp  = lane >> 4;
    const int gl   = lane & 15;

    __shared__ int   s_idx[NROWS_P];
    __shared__ float s_part[4];

    if (tid < W_CTX) {
        s_idx[tid * 11] = outside_word_indices[b * W_CTX + tid];
    } else if (tid >= 16 && tid < 16 + W_CTX * K_NEG) {
        const int r = tid - 16;
        const int w = r / K_NEG;
        const int j = r - w * K_NEG;
        s_idx[w * 11 + 1 + j] = negative_samples[b * W_CTX * K_NEG + r];
    } else if (tid >= 128 && tid < 128 + (NROWS_P - NROWS)) {
        s_idx[NROWS + (tid - 128)] = 0;
    }
    __syncthreads();

    const int ci = center_word_index[b];
    const float4* cp = reinterpret_cast<const float4*>(
        center_vectors + (size_t)ci * D_DIM);
    const float4 c0 = cp[gl];
    const float4 c1 = cp[16 + gl];

    float acc = 0.0f;
#pragma unroll
    for (int p = 0; p < NPASS; ++p) {
        const int r = p * 16 + wave * 4 + grp;
        const int w = r / 11;
        const int j = r - w * 11;
        const int idx = s_idx[r];
        const int oi = s_idx[w * 11];
        const float cf = (oi != 0) ? ((j == 0) ? -1.0f : 1.0f) : 0.0f;

        const float4* rp = reinterpret_cast<const float4*>(
            outside_vectors + (size_t)idx * D_DIM);
        const float4 a0 = rp[gl];
        const float4 a1 = rp[16 + gl];

        float s = c0.x * a0.x;
        s = fmaf(c0.y, a0.y, s);
        s = fmaf(c0.z, a0.z, s);
        s = fmaf(c0.w, a0.w, s);
        s = fmaf(c1.x, a1.x, s);
        s = fmaf(c1.y, a1.y, s);
        s = fmaf(c1.z, a1.z, s);
        s = fmaf(c1.w, a1.w, s);

        s += __shfl_xor(s, 8, 64);
        s += __shfl_xor(s, 4, 64);
        s += __shfl_xor(s, 2, 64);
        s += __shfl_xor(s, 1, 64);

        acc += fabsf(cf) * fast_softplus(cf * s);
    }

    acc += __shfl_xor(acc, 16, 64);
    acc += __shfl_xor(acc, 32, 64);

    if (lane == 0) s_part[wave] = acc;
    __syncthreads();

    if (tid == 0)
        out[b] = s_part[0] + s_part[1] + s_part[2] + s_part[3];
}

extern "C" void kernel_launch(void* const* d_in, const int* in_sizes, int n_in,
                              void* d_out, int out_size, void* d_ws, size_t ws_size,
                              hipStream_t stream) {
    const float* center_vectors       = (const float*)d_in[0];
    const float* outside_vectors      = (const float*)d_in[1];
    const int*   center_word_index    = (const int*)d_in[2];
    const int*   outside_word_indices = (const int*)d_in[3];
    const int*   negative_samples     = (const int*)d_in[4];
    float*       out                  = (float*)d_out;

    const int batch    = in_sizes[2];             // 8192
    const int n_tokens = in_sizes[1] / D_DIM;     // 100000
    const size_t need  = (size_t)n_tokens * D_DIM * sizeof(unsigned short);

    if (ws_size >= need) {
        unsigned short* obf = (unsigned short*)d_ws;
        const int n4 = n_tokens * D_DIM / 4;      // 3.2M float4 groups
        convert_bf16_kernel<<<(n4 + 255) / 256, 256, 0, stream>>>(
            (const float4*)outside_vectors, (ushort4*)obf, n4);
        w2v_bf16_kernel<<<batch, BLK, 0, stream>>>(
            center_vectors, obf, center_word_index,
            outside_word_indices, negative_samples, out);
    } else {
        w2v_f32_kernel<<<batch, BLK, 0, stream>>>(
            center_vectors, outside_vectors, center_word_index,
            outside_word_indices, negative_samples, out);
    }
}